// Round 7
// baseline (1681.236 us; speedup 1.0000x reference)
//
#include <hip/hip_runtime.h>
#include <hip/hip_bf16.h>
#include <hip/hip_cooperative_groups.h>
#include <math.h>

namespace cg = cooperative_groups;

#define N_NODES 50000
#define N_EDGES 800000
#define HDIM 64

#define NBUCKET 392       // buckets of 128 nodes: 392*128 = 50176 >= 50000
#define BSHIFT  7
#define NLOC    128       // nodes per bucket
#define BCAP    3072      // mean 2048, sd ~45 -> ~22 sigma headroom

typedef short bf16x8 __attribute__((ext_vector_type(8)));
typedef float f32x4  __attribute__((ext_vector_type(4)));
typedef unsigned short ushort_t;

__device__ __forceinline__ ushort_t f2bf(float f) {
    __hip_bfloat16 b = __float2bfloat16(f);
    return *(ushort_t*)&b;
}

// ===========================================================================
// MEGA cooperative kernel: whole pipeline, phases separated by grid.sync().
// Grid 2048 x 256, 8 blocks/CU co-resident (LDS 12.8KB union, <=64 VGPR).
// P0 zero -> P1 convert+W+scatter -> P2 sort -> (agg -> mfma) x2 -> sigmoid
// ===========================================================================
__global__ __launch_bounds__(256, 8) void mega(
    const float* __restrict__ features, const float* __restrict__ V,
    const float* __restrict__ comp, const float* __restrict__ loop_w,
    const float* __restrict__ bias, const float* __restrict__ fcw,
    const float* __restrict__ fcb,
    const int* __restrict__ src, const int* __restrict__ dst,
    const int* __restrict__ etype, float* __restrict__ out,
    ushort_t* __restrict__ x_bf, ushort_t* __restrict__ x1_bf,
    ushort_t* __restrict__ y_bf, ushort_t* __restrict__ Wt,
    float* __restrict__ scalar, int* __restrict__ bucketFill,
    int* __restrict__ row_ptr, unsigned int* __restrict__ edges,
    unsigned int* __restrict__ buf)
{
    cg::grid_group grid = cg::this_grid();
    __shared__ __align__(16) char smem[12832];
    const int t  = threadIdx.x;
    const int nb = gridDim.x;
    const int gtid = blockIdx.x * 256 + t;

    // ---------------- P0: zero counters ----------------
    if (gtid < NBUCKET) bucketFill[gtid] = 0;
    if (gtid == NBUCKET) scalar[0] = 0.0f;
    grid.sync();

    // ---------------- P1: feature/W convert + bucket scatter ----------------
    for (int vt = blockIdx.x; vt < 3612; vt += nb) {
        if (vt < 3125) {
            const int i = vt * 256 + t;              // < 800000 float4s
            const float4 v = ((const float4*)features)[i];
            ushort4 o = { f2bf(v.x), f2bf(v.y), f2bf(v.z), f2bf(v.w) };
            *(ushort4*)&x_bf[(size_t)i * 4] = o;
        } else if (vt < 3221) {
            const int e = (vt - 3125) * 256 + t;     // < 24576
            const int l = e / 12288, r = e % 12288;
            const int n = r / 192, k = r % 192;
            const int sel = k >> 6, i = k & 63;
            const float val = (sel < 2) ? V[l * 8192 + sel * 4096 + i * 64 + n]
                                        : loop_w[l * 4096 + i * 64 + n];
            Wt[e] = f2bf(val);
        } else {
            // scatter tile
            int* cnt  = (int*)smem;
            int* base = cnt + NBUCKET;
            const int sb = vt - 3221;
            for (int i = t; i < NBUCKET; i += 256) cnt[i] = 0;
            __syncthreads();
            int rank[8], bkt[8];
            unsigned pay[8];
            bool valid[8];
#pragma unroll
            for (int k = 0; k < 8; ++k) {
                const int e = sb * 2048 + k * 256 + t;
                valid[k] = (e < N_EDGES);
                if (valid[k]) {
                    const int d = dst[e];
                    const int bk = d >> BSHIFT;
                    bkt[k] = bk;
                    pay[k] = (unsigned)src[e] | ((unsigned)etype[e] << 16)
                           | ((unsigned)(d & (NLOC - 1)) << 19);
                    rank[k] = atomicAdd(&cnt[bk], 1);
                }
            }
            __syncthreads();
            for (int i = t; i < NBUCKET; i += 256)
                base[i] = atomicAdd(&bucketFill[i], cnt[i]);
            __syncthreads();
#pragma unroll
            for (int k = 0; k < 8; ++k) {
                if (valid[k]) {
                    const int pos = base[bkt[k]] + rank[k];
                    if (pos < BCAP) buf[bkt[k] * BCAP + pos] = pay[k];
                }
            }
        }
    }
    grid.sync();

    // ---------------- P2: per-bucket sort ----------------
    for (int b = blockIdx.x; b < NBUCKET; b += nb) {
        int* hist  = (int*)smem;
        int* lscan = hist + NLOC;
        int* cnt2  = lscan + NLOC;
        int* sraw  = cnt2 + NLOC;
        int* sexc  = sraw + 448;

        if (t < NLOC) { hist[t] = 0; cnt2[t] = 0; }
        for (int i = t; i < 448; i += 256)
            sraw[i] = (i < NBUCKET) ? bucketFill[i] : 0;
        __syncthreads();

        if (t < 64) {
            int carry = 0;
            for (int c = 0; c < 7; ++c) {
                const int h = sraw[c * 64 + t];
                int x = h;
#pragma unroll
                for (int off = 1; off < 64; off <<= 1) {
                    int u = __shfl_up(x, off, 64);
                    if (t >= off) x += u;
                }
                sexc[c * 64 + t] = carry + x - h;
                carry += __shfl(x, 63, 64);
            }
        }
        __syncthreads();
        const int cntb = min(sraw[b], BCAP);
        const int bb   = sexc[b];

        for (int i0 = t; i0 < cntb; i0 += 1024) {
            const bool v1 = i0 + 256 < cntb, v2 = i0 + 512 < cntb, v3 = i0 + 768 < cntb;
            const unsigned p0 = buf[b * BCAP + i0];
            unsigned p1 = 0, p2 = 0, p3 = 0;
            if (v1) p1 = buf[b * BCAP + i0 + 256];
            if (v2) p2 = buf[b * BCAP + i0 + 512];
            if (v3) p3 = buf[b * BCAP + i0 + 768];
            atomicAdd(&hist[p0 >> 19], 1);
            if (v1) atomicAdd(&hist[p1 >> 19], 1);
            if (v2) atomicAdd(&hist[p2 >> 19], 1);
            if (v3) atomicAdd(&hist[p3 >> 19], 1);
        }
        __syncthreads();

        if (t < 64) {
            int carry = 0;
            for (int c = 0; c < 2; ++c) {
                const int h = hist[c * 64 + t];
                int x = h;
#pragma unroll
                for (int off = 1; off < 64; off <<= 1) {
                    int u = __shfl_up(x, off, 64);
                    if (t >= off) x += u;
                }
                lscan[c * 64 + t] = carry + x - h;
                carry += __shfl(x, 63, 64);
            }
        }
        __syncthreads();

        const int n0 = b << BSHIFT;
        if (t < NLOC) {
            const int g = n0 + t;
            if (g < N_NODES) row_ptr[g] = bb + lscan[t];
        }
        if (b == NBUCKET - 1 && t == 0) row_ptr[N_NODES] = bb + cntb;

        for (int i0 = t; i0 < cntb; i0 += 1024) {
            const bool v1 = i0 + 256 < cntb, v2 = i0 + 512 < cntb, v3 = i0 + 768 < cntb;
            const unsigned p0 = buf[b * BCAP + i0];
            unsigned p1 = 0, p2 = 0, p3 = 0;
            if (v1) p1 = buf[b * BCAP + i0 + 256];
            if (v2) p2 = buf[b * BCAP + i0 + 512];
            if (v3) p3 = buf[b * BCAP + i0 + 768];
            {
                const int d = p0 >> 19;
                const int r = atomicAdd(&cnt2[d], 1);
                edges[bb + lscan[d] + r] = p0;
            }
            if (v1) { const int d = p1 >> 19; const int r = atomicAdd(&cnt2[d], 1);
                      edges[bb + lscan[d] + r] = p1; }
            if (v2) { const int d = p2 >> 19; const int r = atomicAdd(&cnt2[d], 1);
                      edges[bb + lscan[d] + r] = p2; }
            if (v3) { const int d = p3 >> 19; const int r = atomicAdd(&cnt2[d], 1);
                      edges[bb + lscan[d] + r] = p3; }
        }
        __syncthreads();
    }
    grid.sync();

    // ---------------- layers: aggregate -> node transform ----------------
    for (int l = 0; l < 2; ++l) {
        const ushort_t* xin    = l ? x1_bf : x_bf;
        const float*    compl_ = comp + l * 16;
        const bool      fuse   = (l == 1);

        // ---- aggregate (R4 structure: 16-lane group per node) ----
        {
            float* scomp = (float*)smem;
            __syncthreads();
            if (t < 16) scomp[t] = compl_[t];
            __syncthreads();

            const int lane = t & 63;
            const int wv   = t >> 6;
            const int g    = lane >> 4;
            const int fq   = lane & 15;

            for (int tile = blockIdx.x; tile < 3125; tile += nb) {
                const int n   = tile * 16 + wv * 4 + g;   // < 50000 exact
                const int beg = row_ptr[n];
                const int end = row_ptr[n + 1];

                float a0[4], a1[4];
#pragma unroll
                for (int i = 0; i < 4; ++i) { a0[i] = 0.f; a1[i] = 0.f; }

                for (int j = beg; j < end; j += 4) {
                    unsigned p[4];
#pragma unroll
                    for (int k = 0; k < 4; ++k) {
                        const int e = j + k;
                        p[k] = edges[(e < end) ? e : (end - 1)];
                    }
                    uint2 u[4];
#pragma unroll
                    for (int k = 0; k < 4; ++k)
                        u[k] = *(const uint2*)&xin[(size_t)(p[k] & 0xFFFFu) * 64 + fq * 4];
                    float2 c[4];
#pragma unroll
                    for (int k = 0; k < 4; ++k) {
                        c[k] = *(const float2*)&scomp[((p[k] >> 16) & 7u) * 2];
                        if (j + k >= end) { c[k].x = 0.f; c[k].y = 0.f; }
                    }
#pragma unroll
                    for (int k = 0; k < 4; ++k) {
                        const float f0 = __uint_as_float(u[k].x << 16);
                        const float f1 = __uint_as_float(u[k].x & 0xFFFF0000u);
                        const float f2 = __uint_as_float(u[k].y << 16);
                        const float f3 = __uint_as_float(u[k].y & 0xFFFF0000u);
                        a0[0] = fmaf(c[k].x, f0, a0[0]); a1[0] = fmaf(c[k].y, f0, a1[0]);
                        a0[1] = fmaf(c[k].x, f1, a0[1]); a1[1] = fmaf(c[k].y, f1, a1[1]);
                        a0[2] = fmaf(c[k].x, f2, a0[2]); a1[2] = fmaf(c[k].y, f2, a1[2]);
                        a0[3] = fmaf(c[k].x, f3, a0[3]); a1[3] = fmaf(c[k].y, f3, a1[3]);
                    }
                }
                ushort4 s0 = { f2bf(a0[0]), f2bf(a0[1]), f2bf(a0[2]), f2bf(a0[3]) };
                ushort4 s1 = { f2bf(a1[0]), f2bf(a1[1]), f2bf(a1[2]), f2bf(a1[3]) };
                *(ushort4*)&y_bf[(size_t)n * 128 + fq * 4]      = s0;
                *(ushort4*)&y_bf[(size_t)n * 128 + 64 + fq * 4] = s1;
            }
        }
        grid.sync();

        // ---- node transform (32-node tiles, MFMA) ----
        {
            ushort_t* su   = (ushort_t*)smem;                 // 12800 B
            float*    sred = (float*)(smem + 12800);          // 16 B
            const int w    = t >> 6;
            const int lane = t & 63;
            const int c16  = lane & 15;
            const int quad = lane >> 4;
            const ushort_t* Wtl = Wt + l * 12288;

            bf16x8 wf[6];
#pragma unroll
            for (int kf = 0; kf < 6; ++kf)
                wf[kf] = *(const bf16x8*)&Wtl[(w * 16 + c16) * 192 + kf * 32 + quad * 8];
            const float bv = bias[l * 64 + w * 16 + c16];

            float fsum = 0.f;
            for (int tile = blockIdx.x; tile < 1563; tile += nb) {
                __syncthreads();
#pragma unroll
                for (int k = 0; k < 3; ++k) {
                    const int cid = t + 256 * k;      // 0..767 = 32 rows x 24 parts
                    const int row = cid / 24;
                    const int part = cid % 24;
                    const int n = tile * 32 + row;
                    uint4 v = {0u, 0u, 0u, 0u};
                    if (n < N_NODES) {
                        v = (part < 16)
                          ? *(const uint4*)&y_bf[(size_t)n * 128 + part * 8]
                          : *(const uint4*)&xin[(size_t)n * 64 + (part - 16) * 8];
                    }
                    *(uint4*)&su[row * 200 + part * 8] = v;
                }
                __syncthreads();

#pragma unroll
                for (int mt = 0; mt < 2; ++mt) {
                    f32x4 acc = {bv, bv, bv, bv};
#pragma unroll
                    for (int kf = 0; kf < 6; ++kf) {
                        const bf16x8 af =
                            *(const bf16x8*)&su[(mt * 16 + c16) * 200 + kf * 32 + quad * 8];
                        acc = __builtin_amdgcn_mfma_f32_16x16x32_bf16(af, wf[kf], acc, 0, 0, 0);
                    }
                    const int nodeb = tile * 32 + mt * 16 + quad * 4;
                    if (fuse) {
#pragma unroll
                        for (int r = 0; r < 4; ++r) {
                            const int n = nodeb + r;
                            if (n < N_NODES)
                                fsum += acc[r] * fcw[(size_t)n * 64 + w * 16 + c16];
                        }
                    } else {
#pragma unroll
                        for (int r = 0; r < 4; ++r) {
                            const int n = nodeb + r;
                            if (n < N_NODES)
                                x1_bf[(size_t)n * 64 + w * 16 + c16] = f2bf(fmaxf(acc[r], 0.f));
                        }
                    }
                }
            }
            if (fuse) {
#pragma unroll
                for (int off = 32; off; off >>= 1) fsum += __shfl_down(fsum, off, 64);
                __syncthreads();
                if (lane == 0) sred[w] = fsum;
                __syncthreads();
                if (t == 0)
                    atomicAdd(scalar, sred[0] + sred[1] + sred[2] + sred[3]);
            }
        }
        grid.sync();
    }

    // ---------------- final sigmoid ----------------
    if (blockIdx.x == 0 && t == 0) {
        const float v = atomicAdd(scalar, 0.0f) + fcb[0];
        out[0] = 1.0f / (1.0f + expf(-v));
    }
}

// ===========================================================================
// Fallback path: round-4 kernels verbatim (used only if cooperative launch
// is rejected by the runtime/capture).
// ===========================================================================
__global__ __launch_bounds__(256) void prep_kernel(
    const float* __restrict__ features, ushort_t* __restrict__ x_bf,
    const float* __restrict__ V, const float* __restrict__ lw,
    ushort_t* __restrict__ Wt, int* __restrict__ bucketFill,
    float* __restrict__ scalar, int* __restrict__ done)
{
    const int b = blockIdx.x;
    const int t = threadIdx.x;
    if (b < 3125) {
        const int i = b * 256 + t;
        const float4 v = ((const float4*)features)[i];
        ushort4 o = { f2bf(v.x), f2bf(v.y), f2bf(v.z), f2bf(v.w) };
        *(ushort4*)&x_bf[(size_t)i * 4] = o;
    } else if (b < 3221) {
        const int e = (b - 3125) * 256 + t;
        const int l = e / 12288, r = e % 12288;
        const int n = r / 192, k = r % 192;
        const int sel = k >> 6, i = k & 63;
        const float val = (sel < 2) ? V[l * 8192 + sel * 4096 + i * 64 + n]
                                    : lw[l * 4096 + i * 64 + n];
        Wt[e] = f2bf(val);
    } else {
        for (int i = t; i < NBUCKET; i += 256) bucketFill[i] = 0;
        if (t == 0) { scalar[0] = 0.0f; done[0] = 0; }
    }
}

__global__ __launch_bounds__(256) void bucket_scatter(
    const int* __restrict__ src, const int* __restrict__ dst,
    const int* __restrict__ etype, int* __restrict__ bucketFill,
    unsigned int* __restrict__ buf)
{
    __shared__ int cnt[NBUCKET];
    __shared__ int base[NBUCKET];
    const int t = threadIdx.x;
    for (int i = t; i < NBUCKET; i += 256) cnt[i] = 0;
    __syncthreads();
    int rank[8], bkt[8];
    unsigned pay[8];
    bool valid[8];
#pragma unroll
    for (int k = 0; k < 8; ++k) {
        const int e = blockIdx.x * 2048 + k * 256 + t;
        valid[k] = (e < N_EDGES);
        if (valid[k]) {
            const int d = dst[e];
            const int b = d >> BSHIFT;
            bkt[k] = b;
            pay[k] = (unsigned)src[e] | ((unsigned)etype[e] << 16)
                   | ((unsigned)(d & (NLOC - 1)) << 19);
            rank[k] = atomicAdd(&cnt[b], 1);
        }
    }
    __syncthreads();
    for (int i = t; i < NBUCKET; i += 256)
        base[i] = atomicAdd(&bucketFill[i], cnt[i]);
    __syncthreads();
#pragma unroll
    for (int k = 0; k < 8; ++k) {
        if (valid[k]) {
            const int pos = base[bkt[k]] + rank[k];
            if (pos < BCAP) buf[bkt[k] * BCAP + pos] = pay[k];
        }
    }
}

__global__ __launch_bounds__(256) void bucket_sort_k(
    const unsigned int* __restrict__ buf, const int* __restrict__ bucketFill,
    unsigned int* __restrict__ edges, int* __restrict__ row_ptr)
{
    __shared__ int hist[NLOC];
    __shared__ int lscan[NLOC];
    __shared__ int cnt2[NLOC];
    __shared__ int sraw[448];
    __shared__ int sexc[448];
    const int b = blockIdx.x;
    const int t = threadIdx.x;
    if (t < NLOC) { hist[t] = 0; cnt2[t] = 0; }
    for (int i = t; i < 448; i += 256)
        sraw[i] = (i < NBUCKET) ? bucketFill[i] : 0;
    __syncthreads();
    if (t < 64) {
        int carry = 0;
        for (int c = 0; c < 7; ++c) {
            const int h = sraw[c * 64 + t];
            int x = h;
#pragma unroll
            for (int off = 1; off < 64; off <<= 1) {
                int u = __shfl_up(x, off, 64);
                if (t >= off) x += u;
            }
            sexc[c * 64 + t] = carry + x - h;
            carry += __shfl(x, 63, 64);
        }
    }
    __syncthreads();
    const int cntb = min(sraw[b], BCAP);
    const int bb   = sexc[b];
    for (int i0 = t; i0 < cntb; i0 += 1024) {
        const bool v1 = i0 + 256 < cntb, v2 = i0 + 512 < cntb, v3 = i0 + 768 < cntb;
        const unsigned p0 = buf[b * BCAP + i0];
        unsigned p1 = 0, p2 = 0, p3 = 0;
        if (v1) p1 = buf[b * BCAP + i0 + 256];
        if (v2) p2 = buf[b * BCAP + i0 + 512];
        if (v3) p3 = buf[b * BCAP + i0 + 768];
        atomicAdd(&hist[p0 >> 19], 1);
        if (v1) atomicAdd(&hist[p1 >> 19], 1);
        if (v2) atomicAdd(&hist[p2 >> 19], 1);
        if (v3) atomicAdd(&hist[p3 >> 19], 1);
    }
    __syncthreads();
    if (t < 64) {
        int carry = 0;
        for (int c = 0; c < 2; ++c) {
            const int h = hist[c * 64 + t];
            int x = h;
#pragma unroll
            for (int off = 1; off < 64; off <<= 1) {
                int u = __shfl_up(x, off, 64);
                if (t >= off) x += u;
            }
            lscan[c * 64 + t] = carry + x - h;
            carry += __shfl(x, 63, 64);
        }
    }
    __syncthreads();
    const int n0 = b << BSHIFT;
    if (t < NLOC) {
        const int g = n0 + t;
        if (g < N_NODES) row_ptr[g] = bb + lscan[t];
    }
    if (b == NBUCKET - 1 && t == 0) row_ptr[N_NODES] = bb + cntb;
    for (int i0 = t; i0 < cntb; i0 += 1024) {
        const bool v1 = i0 + 256 < cntb, v2 = i0 + 512 < cntb, v3 = i0 + 768 < cntb;
        const unsigned p0 = buf[b * BCAP + i0];
        unsigned p1 = 0, p2 = 0, p3 = 0;
        if (v1) p1 = buf[b * BCAP + i0 + 256];
        if (v2) p2 = buf[b * BCAP + i0 + 512];
        if (v3) p3 = buf[b * BCAP + i0 + 768];
        {
            const int d = p0 >> 19;
            const int r = atomicAdd(&cnt2[d], 1);
            edges[bb + lscan[d] + r] = p0;
        }
        if (v1) { const int d = p1 >> 19; const int r = atomicAdd(&cnt2[d], 1);
                  edges[bb + lscan[d] + r] = p1; }
        if (v2) { const int d = p2 >> 19; const int r = atomicAdd(&cnt2[d], 1);
                  edges[bb + lscan[d] + r] = p2; }
        if (v3) { const int d = p3 >> 19; const int r = atomicAdd(&cnt2[d], 1);
                  edges[bb + lscan[d] + r] = p3; }
    }
}

__global__ __launch_bounds__(256) void aggregate_v4(
    const ushort_t* __restrict__ x, const unsigned int* __restrict__ edges,
    const int* __restrict__ row_ptr, const float* __restrict__ comp_l,
    ushort_t* __restrict__ y)
{
    __shared__ float scomp[16];
    const int t = threadIdx.x;
    if (t < 16) scomp[t] = comp_l[t];
    __syncthreads();
    const int lane = t & 63;
    const int wv   = t >> 6;
    const int g    = lane >> 4;
    const int fq   = lane & 15;
    const int n    = blockIdx.x * 16 + wv * 4 + g;
    const int beg = row_ptr[n];
    const int end = row_ptr[n + 1];
    float a0[4], a1[4];
#pragma unroll
    for (int i = 0; i < 4; ++i) { a0[i] = 0.f; a1[i] = 0.f; }
    for (int j = beg; j < end; j += 4) {
        unsigned p[4];
#pragma unroll
        for (int k = 0; k < 4; ++k) {
            const int e = j + k;
            p[k] = edges[(e < end) ? e : (end - 1)];
        }
        uint2 u[4];
#pragma unroll
        for (int k = 0; k < 4; ++k)
            u[k] = *(const uint2*)&x[(size_t)(p[k] & 0xFFFFu) * 64 + fq * 4];
        float2 c[4];
#pragma unroll
        for (int k = 0; k < 4; ++k) {
            c[k] = *(const float2*)&scomp[((p[k] >> 16) & 7u) * 2];
            if (j + k >= end) { c[k].x = 0.f; c[k].y = 0.f; }
        }
#pragma unroll
        for (int k = 0; k < 4; ++k) {
            const float f0 = __uint_as_float(u[k].x << 16);
            const float f1 = __uint_as_float(u[k].x & 0xFFFF0000u);
            const float f2 = __uint_as_float(u[k].y << 16);
            const float f3 = __uint_as_float(u[k].y & 0xFFFF0000u);
            a0[0] = fmaf(c[k].x, f0, a0[0]); a1[0] = fmaf(c[k].y, f0, a1[0]);
            a0[1] = fmaf(c[k].x, f1, a0[1]); a1[1] = fmaf(c[k].y, f1, a1[1]);
            a0[2] = fmaf(c[k].x, f2, a0[2]); a1[2] = fmaf(c[k].y, f2, a1[2]);
            a0[3] = fmaf(c[k].x, f3, a0[3]); a1[3] = fmaf(c[k].y, f3, a1[3]);
        }
    }
    ushort4 s0 = { f2bf(a0[0]), f2bf(a0[1]), f2bf(a0[2]), f2bf(a0[3]) };
    ushort4 s1 = { f2bf(a1[0]), f2bf(a1[1]), f2bf(a1[2]), f2bf(a1[3]) };
    *(ushort4*)&y[(size_t)n * 128 + fq * 4]      = s0;
    *(ushort4*)&y[(size_t)n * 128 + 64 + fq * 4] = s1;
}

template <bool FUSE>
__global__ __launch_bounds__(256) void mfma_transform(
    const ushort_t* __restrict__ y_bf, const ushort_t* __restrict__ x_bf,
    const ushort_t* __restrict__ Wt, const float* __restrict__ bias,
    const float* __restrict__ fcw, ushort_t* __restrict__ xout,
    float* __restrict__ scalar, const float* __restrict__ fcb,
    int* __restrict__ done, float* __restrict__ outp)
{
    __shared__ __align__(16) ushort_t su[64 * 200];
    __shared__ float sred[4];
    const int t = threadIdx.x;
    const int w = t >> 6;
    const int lane = t & 63;
    const int c16 = lane & 15;
    const int quad = lane >> 4;
    const int tile = blockIdx.x;
    bf16x8 wf[6];
#pragma unroll
    for (int kf = 0; kf < 6; ++kf)
        wf[kf] = *(const bf16x8*)&Wt[(w * 16 + c16) * 192 + kf * 32 + quad * 8];
    const float bv = bias[w * 16 + c16];
#pragma unroll
    for (int k = 0; k < 6; ++k) {
        const int cid = t + 256 * k;
        const int row = cid / 24;
        const int part = cid % 24;
        const int n = tile * 64 + row;
        uint4 v = {0u, 0u, 0u, 0u};
        if (n < N_NODES) {
            v = (part < 16) ? *(const uint4*)&y_bf[(size_t)n * 128 + part * 8]
                            : *(const uint4*)&x_bf[(size_t)n * 64 + (part - 16) * 8];
        }
        *(uint4*)&su[row * 200 + part * 8] = v;
    }
    __syncthreads();
    float fsum = 0.f;
#pragma unroll
    for (int mt = 0; mt < 4; ++mt) {
        f32x4 acc = {bv, bv, bv, bv};
#pragma unroll
        for (int kf = 0; kf < 6; ++kf) {
            const bf16x8 af =
                *(const bf16x8*)&su[(mt * 16 + c16) * 200 + kf * 32 + quad * 8];
            acc = __builtin_amdgcn_mfma_f32_16x16x32_bf16(af, wf[kf], acc, 0, 0, 0);
        }
        const int nodeb = tile * 64 + mt * 16 + quad * 4;
        if (FUSE) {
#pragma unroll
            for (int r = 0; r < 4; ++r) {
                const int n = nodeb + r;
                if (n < N_NODES)
                    fsum += acc[r] * fcw[(size_t)n * 64 + w * 16 + c16];
            }
        } else {
#pragma unroll
            for (int r = 0; r < 4; ++r) {
                const int n = nodeb + r;
                if (n < N_NODES)
                    xout[(size_t)n * 64 + w * 16 + c16] = f2bf(fmaxf(acc[r], 0.f));
            }
        }
    }
    if (FUSE) {
#pragma unroll
        for (int off = 32; off; off >>= 1) fsum += __shfl_down(fsum, off, 64);
        if (lane == 0) sred[w] = fsum;
        __syncthreads();
        if (t == 0) {
            atomicAdd(scalar, sred[0] + sred[1] + sred[2] + sred[3]);
            __threadfence();
            const int ticket = atomicAdd(done, 1);
            if (ticket == (int)gridDim.x - 1) {
                const float v = atomicAdd(scalar, 0.0f) + fcb[0];
                outp[0] = 1.0f / (1.0f + expf(-v));
            }
        }
    }
}

// ---------------------------------------------------------------------------
extern "C" void kernel_launch(void* const* d_in, const int* in_sizes, int n_in,
                              void* d_out, int out_size, void* d_ws, size_t ws_size,
                              hipStream_t stream)
{
    const float* features = (const float*)d_in[0];
    const float* V        = (const float*)d_in[1];
    const float* comp     = (const float*)d_in[2];
    const float* loop_w   = (const float*)d_in[3];
    const float* bias     = (const float*)d_in[4];
    const float* fc_w     = (const float*)d_in[5];
    const float* fc_b     = (const float*)d_in[6];
    const int*   src      = (const int*)d_in[7];
    const int*   dst      = (const int*)d_in[8];
    const int*   etype    = (const int*)d_in[9];
    float* out = (float*)d_out;

    char* ws = (char*)d_ws;
    ushort_t*     y_bf    = (ushort_t*)(ws);                 // 12,800,000 B
    ushort_t*     x_bf    = (ushort_t*)(ws + 12800000);      //  6,400,000 B
    ushort_t*     x1_bf   = (ushort_t*)(ws + 19200000);      //  6,400,000 B
    ushort_t*     Wt      = (ushort_t*)(ws + 25600000);      //     49,152 B
    float*        scalar  = (float*)   (ws + 25649152);      //          4 B
    int*          done    = (int*)     (ws + 25649156);      //          4 B
    int*          bucketFill = (int*)  (ws + 25649280);      //      1,568 B
    int*          row_ptr = (int*)     (ws + 25650944);      //    200,004 B
    unsigned int* edges   = (unsigned int*)(ws + 25851008);  //  3,200,000 B
    unsigned int* buf     = (unsigned int*)(ws + 29051008);  //  4,816,896 B

    // ---- cooperative mega-kernel (primary path) ----
    void* kargs[] = {
        (void*)&features, (void*)&V, (void*)&comp, (void*)&loop_w,
        (void*)&bias, (void*)&fc_w, (void*)&fc_b,
        (void*)&src, (void*)&dst, (void*)&etype, (void*)&out,
        (void*)&x_bf, (void*)&x1_bf, (void*)&y_bf, (void*)&Wt,
        (void*)&scalar, (void*)&bucketFill, (void*)&row_ptr,
        (void*)&edges, (void*)&buf
    };
    hipError_t err = hipLaunchCooperativeKernel(
        (const void*)mega, dim3(2048), dim3(256), kargs, 0, stream);
    if (err == hipSuccess) return;

    // ---- fallback: round-4 pipeline ----
    const int aggBlocks = N_NODES / 16;
    const int mtBlocks  = (N_NODES + 63) / 64;
    const int k1Blocks  = (N_EDGES + 2047) / 2048;
    prep_kernel<<<3222, 256, 0, stream>>>(features, x_bf, V, loop_w, Wt,
                                          bucketFill, scalar, done);
    bucket_scatter<<<k1Blocks, 256, 0, stream>>>(src, dst, etype, bucketFill, buf);
    bucket_sort_k<<<NBUCKET, 256, 0, stream>>>(buf, bucketFill, edges, row_ptr);
    aggregate_v4<<<aggBlocks, 256, 0, stream>>>(x_bf, edges, row_ptr, comp, y_bf);
    mfma_transform<false><<<mtBlocks, 256, 0, stream>>>(
        y_bf, x_bf, Wt, bias, nullptr, x1_bf, nullptr, nullptr, nullptr, nullptr);
    aggregate_v4<<<aggBlocks, 256, 0, stream>>>(x1_bf, edges, row_ptr, comp + 16, y_bf);
    mfma_transform<true><<<mtBlocks, 256, 0, stream>>>(
        y_bf, x1_bf, Wt + 12288, bias + 64, fc_w, nullptr, scalar, fc_b, done, out);
}

// Round 8
// 191.007 us; speedup vs baseline: 8.8020x; 8.8020x over previous
//
#include <hip/hip_runtime.h>
#include <hip/hip_bf16.h>
#include <math.h>

#define N_NODES 50000
#define N_EDGES 800000
#define HDIM 64

#define NBUCKET 392       // buckets of 128 nodes: 392*128 = 50176 >= 50000
#define BSHIFT  7
#define NLOC    128       // nodes per bucket
#define BCAP    3072      // mean 2048, sd ~45 -> ~22 sigma headroom
#define FCW_LD  50048     // padded leading dim of transposed fc_w (zero pad)

typedef short bf16x8 __attribute__((ext_vector_type(8)));
typedef float f32x4  __attribute__((ext_vector_type(4)));
typedef unsigned short ushort_t;

__device__ __forceinline__ ushort_t f2bf(float f) {
    __hip_bfloat16 b = __float2bfloat16(f);
    return *(ushort_t*)&b;
}

// ---------------------------------------------------------------------------
// Prep: [0,3125) features->bf16; [3125,3221) W transpose+convert;
// [3221,4003) fc_w transpose->bf16 [64][50048] (pad zeroed);
// block 4003: zero bucketFill + scalar + done.
// ---------------------------------------------------------------------------
__global__ __launch_bounds__(256) void prep_kernel(
    const float* __restrict__ features, ushort_t* __restrict__ x_bf,
    const float* __restrict__ V, const float* __restrict__ lw,
    const float* __restrict__ fcw, ushort_t* __restrict__ fcw_bf,
    ushort_t* __restrict__ Wt, int* __restrict__ bucketFill,
    float* __restrict__ scalar, int* __restrict__ done)
{
    __shared__ float tile[64][65];
    const int b = blockIdx.x;
    const int t = threadIdx.x;
    if (b < 3125) {
        const int i = b * 256 + t;                   // < 800000 float4s
        const float4 v = ((const float4*)features)[i];
        ushort4 o = { f2bf(v.x), f2bf(v.y), f2bf(v.z), f2bf(v.w) };
        *(ushort4*)&x_bf[(size_t)i * 4] = o;
    } else if (b < 3221) {
        const int e = (b - 3125) * 256 + t;          // < 24576
        const int l = e / 12288, r = e % 12288;
        const int n = r / 192, k = r % 192;
        const int sel = k >> 6, i = k & 63;
        const float val = (sel < 2) ? V[l * 8192 + sel * 4096 + i * 64 + n]
                                    : lw[l * 4096 + i * 64 + n];
        Wt[e] = f2bf(val);
    } else if (b < 4003) {
        // fc_w transpose: [N,64] f32 -> [64][FCW_LD] bf16, pad = 0
        const int n0 = (b - 3221) * 64;
#pragma unroll
        for (int k = 0; k < 16; ++k) {
            const int idx = t + k * 256;             // 0..4095
            const int row = idx >> 6, col = idx & 63;
            const int n = n0 + row;
            tile[row][col] = (n < N_NODES) ? fcw[(size_t)n * 64 + col] : 0.f;
        }
        __syncthreads();
#pragma unroll
        for (int k = 0; k < 16; ++k) {
            const int idx = t + k * 256;
            const int col = idx >> 6, j = idx & 63;
            fcw_bf[(size_t)col * FCW_LD + n0 + j] = f2bf(tile[j][col]);
        }
    } else {
        for (int i = t; i < NBUCKET; i += 256) bucketFill[i] = 0;
        if (t == 0) { scalar[0] = 0.0f; done[0] = 0; }
    }
}

// ---------------------------------------------------------------------------
// K1: bucket scatter (R4 verbatim).
// ---------------------------------------------------------------------------
__global__ __launch_bounds__(256) void bucket_scatter(
    const int* __restrict__ src, const int* __restrict__ dst,
    const int* __restrict__ etype, int* __restrict__ bucketFill,
    unsigned int* __restrict__ buf)
{
    __shared__ int cnt[NBUCKET];
    __shared__ int base[NBUCKET];
    const int t = threadIdx.x;
    for (int i = t; i < NBUCKET; i += 256) cnt[i] = 0;
    __syncthreads();

    int rank[8], bkt[8];
    unsigned pay[8];
    bool valid[8];
#pragma unroll
    for (int k = 0; k < 8; ++k) {
        const int e = blockIdx.x * 2048 + k * 256 + t;
        valid[k] = (e < N_EDGES);
        if (valid[k]) {
            const int d = dst[e];
            const int b = d >> BSHIFT;
            bkt[k] = b;
            pay[k] = (unsigned)src[e] | ((unsigned)etype[e] << 16)
                   | ((unsigned)(d & (NLOC - 1)) << 19);
            rank[k] = atomicAdd(&cnt[b], 1);
        }
    }
    __syncthreads();
    for (int i = t; i < NBUCKET; i += 256)
        base[i] = atomicAdd(&bucketFill[i], cnt[i]);
    __syncthreads();
#pragma unroll
    for (int k = 0; k < 8; ++k) {
        if (valid[k]) {
            const int pos = base[bkt[k]] + rank[k];
            if (pos < BCAP) buf[bkt[k] * BCAP + pos] = pay[k];
        }
    }
}

// ---------------------------------------------------------------------------
// K2: per-bucket sort (R4 verbatim).
// ---------------------------------------------------------------------------
__global__ __launch_bounds__(256) void bucket_sort(
    const unsigned int* __restrict__ buf, const int* __restrict__ bucketFill,
    unsigned int* __restrict__ edges, int* __restrict__ row_ptr)
{
    __shared__ int hist[NLOC];
    __shared__ int lscan[NLOC];
    __shared__ int cnt2[NLOC];
    __shared__ int sraw[448];
    __shared__ int sexc[448];
    const int b = blockIdx.x;
    const int t = threadIdx.x;

    if (t < NLOC) { hist[t] = 0; cnt2[t] = 0; }
    for (int i = t; i < 448; i += 256)
        sraw[i] = (i < NBUCKET) ? bucketFill[i] : 0;
    __syncthreads();

    if (t < 64) {
        int carry = 0;
        for (int c = 0; c < 7; ++c) {
            const int h = sraw[c * 64 + t];
            int x = h;
#pragma unroll
            for (int off = 1; off < 64; off <<= 1) {
                int u = __shfl_up(x, off, 64);
                if (t >= off) x += u;
            }
            sexc[c * 64 + t] = carry + x - h;
            carry += __shfl(x, 63, 64);
        }
    }
    __syncthreads();
    const int cntb = min(sraw[b], BCAP);
    const int bb   = sexc[b];

    for (int i0 = t; i0 < cntb; i0 += 1024) {
        const bool v1 = i0 + 256 < cntb, v2 = i0 + 512 < cntb, v3 = i0 + 768 < cntb;
        const unsigned p0 = buf[b * BCAP + i0];
        unsigned p1 = 0, p2 = 0, p3 = 0;
        if (v1) p1 = buf[b * BCAP + i0 + 256];
        if (v2) p2 = buf[b * BCAP + i0 + 512];
        if (v3) p3 = buf[b * BCAP + i0 + 768];
        atomicAdd(&hist[p0 >> 19], 1);
        if (v1) atomicAdd(&hist[p1 >> 19], 1);
        if (v2) atomicAdd(&hist[p2 >> 19], 1);
        if (v3) atomicAdd(&hist[p3 >> 19], 1);
    }
    __syncthreads();

    if (t < 64) {
        int carry = 0;
        for (int c = 0; c < 2; ++c) {
            const int h = hist[c * 64 + t];
            int x = h;
#pragma unroll
            for (int off = 1; off < 64; off <<= 1) {
                int u = __shfl_up(x, off, 64);
                if (t >= off) x += u;
            }
            lscan[c * 64 + t] = carry + x - h;
            carry += __shfl(x, 63, 64);
        }
    }
    __syncthreads();

    const int n0 = b << BSHIFT;
    if (t < NLOC) {
        const int g = n0 + t;
        if (g < N_NODES) row_ptr[g] = bb + lscan[t];
    }
    if (b == NBUCKET - 1 && t == 0) row_ptr[N_NODES] = bb + cntb;

    for (int i0 = t; i0 < cntb; i0 += 1024) {
        const bool v1 = i0 + 256 < cntb, v2 = i0 + 512 < cntb, v3 = i0 + 768 < cntb;
        const unsigned p0 = buf[b * BCAP + i0];
        unsigned p1 = 0, p2 = 0, p3 = 0;
        if (v1) p1 = buf[b * BCAP + i0 + 256];
        if (v2) p2 = buf[b * BCAP + i0 + 512];
        if (v3) p3 = buf[b * BCAP + i0 + 768];
        {
            const int d = p0 >> 19;
            const int r = atomicAdd(&cnt2[d], 1);
            edges[bb + lscan[d] + r] = p0;
        }
        if (v1) { const int d = p1 >> 19; const int r = atomicAdd(&cnt2[d], 1);
                  edges[bb + lscan[d] + r] = p1; }
        if (v2) { const int d = p2 >> 19; const int r = atomicAdd(&cnt2[d], 1);
                  edges[bb + lscan[d] + r] = p2; }
        if (v3) { const int d = p3 >> 19; const int r = atomicAdd(&cnt2[d], 1);
                  edges[bb + lscan[d] + r] = p3; }
    }
}

// ---------------------------------------------------------------------------
// Aggregate v4 (R4 verbatim): 16-lane group per node, 4 nodes/wave,
// 3125 blocks, 4 edges in flight per lane group.
// ---------------------------------------------------------------------------
__global__ __launch_bounds__(256) void aggregate_v4(
    const ushort_t* __restrict__ x,      // [N,64] bf16
    const unsigned int* __restrict__ edges,
    const int* __restrict__ row_ptr,
    const float* __restrict__ comp_l,    // [8,2] f32
    ushort_t* __restrict__ y)            // [N,128] bf16
{
    __shared__ float scomp[16];
    const int t = threadIdx.x;
    if (t < 16) scomp[t] = comp_l[t];
    __syncthreads();

    const int lane = t & 63;
    const int wv   = t >> 6;
    const int g    = lane >> 4;          // node slot within wave (0..3)
    const int fq   = lane & 15;          // feature quad
    const int n    = blockIdx.x * 16 + wv * 4 + g;   // 3125*16 = 50000 exact

    const int beg = row_ptr[n];
    const int end = row_ptr[n + 1];

    float a0[4], a1[4];
#pragma unroll
    for (int i = 0; i < 4; ++i) { a0[i] = 0.f; a1[i] = 0.f; }

    for (int j = beg; j < end; j += 4) {
        unsigned p[4];
#pragma unroll
        for (int k = 0; k < 4; ++k) {
            const int e = j + k;
            p[k] = edges[(e < end) ? e : (end - 1)];
        }
        uint2 u[4];
#pragma unroll
        for (int k = 0; k < 4; ++k)
            u[k] = *(const uint2*)&x[(size_t)(p[k] & 0xFFFFu) * 64 + fq * 4];
        float2 c[4];
#pragma unroll
        for (int k = 0; k < 4; ++k) {
            c[k] = *(const float2*)&scomp[((p[k] >> 16) & 7u) * 2];
            if (j + k >= end) { c[k].x = 0.f; c[k].y = 0.f; }
        }
#pragma unroll
        for (int k = 0; k < 4; ++k) {
            const float f0 = __uint_as_float(u[k].x << 16);
            const float f1 = __uint_as_float(u[k].x & 0xFFFF0000u);
            const float f2 = __uint_as_float(u[k].y << 16);
            const float f3 = __uint_as_float(u[k].y & 0xFFFF0000u);
            a0[0] = fmaf(c[k].x, f0, a0[0]); a1[0] = fmaf(c[k].y, f0, a1[0]);
            a0[1] = fmaf(c[k].x, f1, a0[1]); a1[1] = fmaf(c[k].y, f1, a1[1]);
            a0[2] = fmaf(c[k].x, f2, a0[2]); a1[2] = fmaf(c[k].y, f2, a1[2]);
            a0[3] = fmaf(c[k].x, f3, a0[3]); a1[3] = fmaf(c[k].y, f3, a1[3]);
        }
    }

    ushort4 s0 = { f2bf(a0[0]), f2bf(a0[1]), f2bf(a0[2]), f2bf(a0[3]) };
    ushort4 s1 = { f2bf(a1[0]), f2bf(a1[1]), f2bf(a1[2]), f2bf(a1[3]) };
    *(ushort4*)&y[(size_t)n * 128 + fq * 4]      = s0;
    *(ushort4*)&y[(size_t)n * 128 + 64 + fq * 4] = s1;
}

// ---------------------------------------------------------------------------
// MFMA node transform: h[0:64] = U[64x192] @ W[192x64] + bias, U=[y0,y1,x]
//  !FUSE: relu(h) -> LDS bounce -> coalesced uint4 stores.
//  FUSE: h . fc_w via transposed bf16 fcw (8B vector loads, zero-padded);
//        last block applies sigmoid.
// ---------------------------------------------------------------------------
template <bool FUSE>
__global__ __launch_bounds__(256) void mfma_transform(
    const ushort_t* __restrict__ y_bf,   // [N,128]
    const ushort_t* __restrict__ x_bf,   // [N,64]
    const ushort_t* __restrict__ Wt,     // [64,192] this layer (n-major)
    const float* __restrict__ bias,      // [64] f32
    const ushort_t* __restrict__ fcwbf,  // [64][FCW_LD] bf16 (FUSE)
    ushort_t* __restrict__ xout,         // [N,64] (!FUSE)
    float* __restrict__ scalar,          // [1]    (FUSE)
    const float* __restrict__ fcb,       // [1]    (FUSE)
    int* __restrict__ done,              // [1]    (FUSE)
    float* __restrict__ outp)            // [1]    (FUSE)
{
    __shared__ __align__(16) ushort_t su[64 * 200];   // 200 = 192 + 8 pad
    __shared__ float sred[4];
    const int t = threadIdx.x;
    const int w = t >> 6;
    const int lane = t & 63;
    const int c16 = lane & 15;
    const int quad = lane >> 4;
    const int tile = blockIdx.x;

    bf16x8 wf[6];
#pragma unroll
    for (int kf = 0; kf < 6; ++kf)
        wf[kf] = *(const bf16x8*)&Wt[(w * 16 + c16) * 192 + kf * 32 + quad * 8];
    const float bv = bias[w * 16 + c16];

#pragma unroll
    for (int k = 0; k < 6; ++k) {
        const int cid = t + 256 * k;          // 0..1535
        const int row = cid / 24;
        const int part = cid % 24;
        const int n = tile * 64 + row;
        uint4 v = {0u, 0u, 0u, 0u};
        if (n < N_NODES) {
            v = (part < 16) ? *(const uint4*)&y_bf[(size_t)n * 128 + part * 8]
                            : *(const uint4*)&x_bf[(size_t)n * 64 + (part - 16) * 8];
        }
        *(uint4*)&su[row * 200 + part * 8] = v;
    }
    __syncthreads();

    float fsum = 0.f;
    float accs[4][4];                     // keep all mt results in registers
#pragma unroll
    for (int mt = 0; mt < 4; ++mt) {
        f32x4 acc = {bv, bv, bv, bv};
#pragma unroll
        for (int kf = 0; kf < 6; ++kf) {
            const bf16x8 af =
                *(const bf16x8*)&su[(mt * 16 + c16) * 200 + kf * 32 + quad * 8];
            acc = __builtin_amdgcn_mfma_f32_16x16x32_bf16(af, wf[kf], acc, 0, 0, 0);
        }
        if (FUSE) {
            // transposed bf16 fc_w: 4 consecutive nodes = one 8B load; pad=0
            const int nodeb = tile * 64 + mt * 16 + quad * 4;
            const uint2 wv2 = *(const uint2*)
                &fcwbf[(size_t)(w * 16 + c16) * FCW_LD + nodeb];
            const float g0 = __uint_as_float(wv2.x << 16);
            const float g1 = __uint_as_float(wv2.x & 0xFFFF0000u);
            const float g2 = __uint_as_float(wv2.y << 16);
            const float g3 = __uint_as_float(wv2.y & 0xFFFF0000u);
            fsum = fmaf(acc[0], g0, fsum);
            fsum = fmaf(acc[1], g1, fsum);
            fsum = fmaf(acc[2], g2, fsum);
            fsum = fmaf(acc[3], g3, fsum);
        } else {
#pragma unroll
            for (int r = 0; r < 4; ++r) accs[mt][r] = acc[r];
        }
    }

    if (FUSE) {
#pragma unroll
        for (int off = 32; off; off >>= 1) fsum += __shfl_down(fsum, off, 64);
        if (lane == 0) sred[w] = fsum;
        __syncthreads();
        if (t == 0) {
            atomicAdd(scalar, sred[0] + sred[1] + sred[2] + sred[3]);
            __threadfence();
            const int ticket = atomicAdd(done, 1);
            if (ticket == (int)gridDim.x - 1) {
                const float v = atomicAdd(scalar, 0.0f) + fcb[0];
                outp[0] = 1.0f / (1.0f + expf(-v));
            }
        }
    } else {
        // LDS bounce: bf16 relu(h) -> stride-72 tile -> coalesced uint4 stores
        __syncthreads();                  // all su reads complete
        ushort_t* sx = su;                // reuse (64 rows x 72, 16B-aligned)
#pragma unroll
        for (int mt = 0; mt < 4; ++mt) {
#pragma unroll
            for (int r = 0; r < 4; ++r) {
                const int row = mt * 16 + quad * 4 + r;
                sx[row * 72 + w * 16 + c16] = f2bf(fmaxf(accs[mt][r], 0.f));
            }
        }
        __syncthreads();
#pragma unroll
        for (int k = 0; k < 2; ++k) {
            const int idx = t + k * 256;          // 0..511 = 64 rows x 8 octets
            const int row = idx >> 3, c8 = (idx & 7) * 8;
            const int n = tile * 64 + row;
            if (n < N_NODES)
                *(uint4*)&xout[(size_t)n * 64 + c8] = *(const uint4*)&sx[row * 72 + c8];
        }
    }
}

// ---------------------------------------------------------------------------
extern "C" void kernel_launch(void* const* d_in, const int* in_sizes, int n_in,
                              void* d_out, int out_size, void* d_ws, size_t ws_size,
                              hipStream_t stream)
{
    const float* features = (const float*)d_in[0];  // [50000, 64]
    const float* V        = (const float*)d_in[1];  // [2, 2, 64, 64]
    const float* comp     = (const float*)d_in[2];  // [2, 8, 2]
    const float* loop_w   = (const float*)d_in[3];  // [2, 64, 64]
    const float* bias     = (const float*)d_in[4];  // [2, 64]
    const float* fc_w     = (const float*)d_in[5];  // [1, 50000*64]
    const float* fc_b     = (const float*)d_in[6];  // [1]
    const int*   src      = (const int*)d_in[7];
    const int*   dst      = (const int*)d_in[8];
    const int*   etype    = (const int*)d_in[9];
    float* out = (float*)d_out;

    char* ws = (char*)d_ws;
    ushort_t*     y_bf    = (ushort_t*)(ws);                 // 12,800,000 B
    ushort_t*     x_bf    = (ushort_t*)(ws + 12800000);      //  6,400,000 B
    ushort_t*     x1_bf   = (ushort_t*)(ws + 19200000);      //  6,400,000 B
    ushort_t*     Wt      = (ushort_t*)(ws + 25600000);      //     49,152 B
    ushort_t*     fcw_bf  = (ushort_t*)(ws + 25649152);      //  6,406,144 B
    float*        scalar  = (float*)   (ws + 32055296);      //          4 B
    int*          done    = (int*)     (ws + 32055300);      //          4 B
    int*          bucketFill = (int*)  (ws + 32055424);      //      1,568 B
    int*          row_ptr = (int*)     (ws + 32057344);      //    200,004 B
    unsigned int* edges   = (unsigned int*)(ws + 32257536);  //  3,200,000 B
    unsigned int* buf     = (unsigned int*)(ws + 35457536);  //  4,816,896 B
                                                             // end ~40.3 MB

    const int aggBlocks = N_NODES / 16;             // 3125 (exact)
    const int mtBlocks  = (N_NODES + 63) / 64;      // 782
    const int k1Blocks  = (N_EDGES + 2047) / 2048;  // 391
    const int prepBlocks = 3125 + 96 + 782 + 1;     // 4004

    // ---- prep (bf16 converts + fc_w transpose + zero counters) + CSR ----
    prep_kernel<<<prepBlocks, 256, 0, stream>>>(features, x_bf, V, loop_w,
                                                fc_w, fcw_bf, Wt,
                                                bucketFill, scalar, done);
    bucket_scatter<<<k1Blocks, 256, 0, stream>>>(src, dst, etype, bucketFill, buf);
    bucket_sort<<<NBUCKET, 256, 0, stream>>>(buf, bucketFill, edges, row_ptr);

    // ---- layer 0 ----
    aggregate_v4<<<aggBlocks, 256, 0, stream>>>(x_bf, edges, row_ptr, comp, y_bf);
    mfma_transform<false><<<mtBlocks, 256, 0, stream>>>(
        y_bf, x_bf, Wt, bias, nullptr, x1_bf, nullptr, nullptr, nullptr, nullptr);

    // ---- layer 1 + fused FC dot + last-block sigmoid ----
    aggregate_v4<<<aggBlocks, 256, 0, stream>>>(x1_bf, edges, row_ptr, comp + 16, y_bf);
    mfma_transform<true><<<mtBlocks, 256, 0, stream>>>(
        y_bf, x1_bf, Wt + 12288, bias + 64, fcw_bf, nullptr, scalar, fc_b, done, out);
}